// Round 1
// baseline (224.339 us; speedup 1.0000x reference)
//
#include <hip/hip_runtime.h>
#include <hip/hip_bf16.h>

typedef __attribute__((ext_vector_type(8))) __bf16 bf16x8;
typedef __attribute__((ext_vector_type(4))) __bf16 bf16x4;
typedef __attribute__((ext_vector_type(4))) float f32x4;

#define N_SEQ   2048
#define N_BATCH 32
#define DIM_U   1024
#define DIM_A   512
#define NROWS   (N_BATCH * N_SEQ)   /* 65536 */
#define MA_ELEMS ((size_t)NROWS * DIM_U) /* 67108864 */

__device__ __forceinline__ float tanh_fast(float x) {
    // tanh(x) = (e^{2x}-1)/(e^{2x}+1); clamp avoids inf/inf
    x = fminf(fmaxf(x, -15.f), 15.f);
    float e = __expf(2.f * x);
    return (e - 1.f) * __builtin_amdgcn_rcpf(e + 1.f);
}

// ---------------------------------------------------------------------------
// kernel 0: pack W (1024x512 f32, k-major) into bf16 MFMA-staging order.
// Wp[g*8 + j] = bf16(W[(s*32 + k16*8 + j)*512 + n]),  g = s*2048 + k16*512 + n
// so each K-step s is a contiguous 32KB block laid out [k16][n][8 k-elems].
__global__ void wpack_kernel(const float* __restrict__ W, __bf16* __restrict__ Wp) {
    int g = blockIdx.x * 256 + threadIdx.x;          // 0..65535
    int s = g >> 11, k16 = (g >> 9) & 3, n = g & 511;
    int kbase = s * 32 + k16 * 8;
    bf16x8 o;
#pragma unroll
    for (int j = 0; j < 8; ++j) o[j] = (__bf16)W[(kbase + j) * 512 + n];
    *reinterpret_cast<bf16x8*>(Wp + (size_t)g * 8) = o;
}

// ---------------------------------------------------------------------------
// kernel 1: scores[row] = sum_d tanh( (H@W)[row,d] + Bb[d] ) * U[d]
// One WG = 64 rows x 512 cols (all of da), K=1024 in 32 steps of BK=32.
// 8 waves, each wave owns a 64-col chunk: Mr=4 (16x16 row frags) x Nr=4.
// LDS: A dbuf 2x4KB (layout [k16][row][16B]) + B 32KB (layout [k16][n][16B]).
#define LDS_A1 4096
#define LDS_B  8192

__global__ __launch_bounds__(512, 2) void score_gemm_kernel(
    const float* __restrict__ H, const __bf16* __restrict__ Wp,
    const float* __restrict__ Bb, const float* __restrict__ Uv,
    float* __restrict__ scores)
{
    __shared__ __align__(16) char lds[40960];
    const int tid  = threadIdx.x;
    const int lane = tid & 63;
    const int wid  = tid >> 6;     // 0..7
    const int c15  = lane & 15;
    const int hi   = lane >> 4;    // 0..3 (= k16 for frag reads)
    const long rowbase = (long)blockIdx.x * 64;

    // A staging: 512 threads -> 64 rows x 4 k16-slots x 2 float4-halves
    const int ar   = tid >> 3;          // row 0..63
    const int ak16 = (tid >> 1) & 3;    // 0..3
    const int ah   = tid & 1;           // half
    const float* aglob = H + (rowbase + ar) * DIM_U + ak16 * 8 + ah * 4;
    char* const awr = lds + ak16 * 1024 + ar * 16 + ah * 8;

    // B staging: 4 global_load_lds issues per thread per K-step.
    // issue i: LDS off = LDS_B + i*8192 + wid*1024 (+ lane*16 by HW)
    //          global  = Wp + s*16384 + i*4096 + (wid*64+lane)*8
    const __bf16* bglob = Wp + (wid * 64 + lane) * 8;

    f32x4 acc[4][4];
#pragma unroll
    for (int m = 0; m < 4; ++m)
#pragma unroll
        for (int n = 0; n < 4; ++n) acc[m][n] = f32x4{0.f, 0.f, 0.f, 0.f};

    // ---- prologue: stage step 0
    {
        f32x4 v = *reinterpret_cast<const f32x4*>(aglob);
        bf16x4 p = {(__bf16)v.x, (__bf16)v.y, (__bf16)v.z, (__bf16)v.w};
        *reinterpret_cast<bf16x4*>(awr) = p;
#pragma unroll
        for (int i = 0; i < 4; ++i)
            __builtin_amdgcn_global_load_lds(
                (const __attribute__((address_space(1))) void*)(const void*)(bglob + i * 4096),
                (__attribute__((address_space(3))) void*)(void*)(lds + LDS_B + i * 8192 + wid * 1024),
                16, 0, 0);
    }
    __syncthreads();

    // frag base offsets
    const int aoff_base = hi * 1024 + c15 * 16;                       // + cur*4096 + m*256
    const int boff_base = LDS_B + hi * 8192 + (wid * 64 + c15) * 16;  // + nn*256

    for (int s = 0; s < 32; ++s) {
        const int cur = s & 1;
        f32x4 nf;
        if (s < 31) nf = *reinterpret_cast<const f32x4*>(aglob + (s + 1) * 32);

        bf16x8 afr[4], bfr[4];
        const char* ab = lds + cur * 4096 + aoff_base;
        const char* bb = lds + boff_base;
#pragma unroll
        for (int m = 0; m < 4; ++m)
            afr[m] = *reinterpret_cast<const bf16x8*>(ab + m * 256);
#pragma unroll
        for (int n = 0; n < 4; ++n)
            bfr[n] = *reinterpret_cast<const bf16x8*>(bb + n * 256);
#pragma unroll
        for (int m = 0; m < 4; ++m)
#pragma unroll
            for (int n = 0; n < 4; ++n)
                acc[m][n] = __builtin_amdgcn_mfma_f32_16x16x32_bf16(afr[m], bfr[n], acc[m][n], 0, 0, 0);

        __syncthreads();   // all waves done reading B before overwrite
        if (s < 31) {
            bf16x4 p = {(__bf16)nf.x, (__bf16)nf.y, (__bf16)nf.z, (__bf16)nf.w};
            *reinterpret_cast<bf16x4*>(awr + (cur ^ 1) * 4096) = p;
            const __bf16* bg = bglob + (size_t)(s + 1) * 16384;
#pragma unroll
            for (int i = 0; i < 4; ++i)
                __builtin_amdgcn_global_load_lds(
                    (const __attribute__((address_space(1))) void*)(const void*)(bg + i * 4096),
                    (__attribute__((address_space(3))) void*)(void*)(lds + LDS_B + i * 8192 + wid * 1024),
                    16, 0, 0);
        }
        __syncthreads();   // staging complete (compiler drains vmcnt/lgkmcnt)
    }

    // ---- epilogue: tanh(+bias) * U, reduce over columns
    float bias[4], uu[4];
#pragma unroll
    for (int n = 0; n < 4; ++n) {
        int col = wid * 64 + n * 16 + c15;
        bias[n] = Bb[col];
        uu[n]   = Uv[col];
    }
    float psum[4][4];
#pragma unroll
    for (int m = 0; m < 4; ++m)
#pragma unroll
        for (int r = 0; r < 4; ++r) psum[m][r] = 0.f;
#pragma unroll
    for (int m = 0; m < 4; ++m)
#pragma unroll
        for (int n = 0; n < 4; ++n)
#pragma unroll
            for (int r = 0; r < 4; ++r)
                psum[m][r] += tanh_fast(acc[m][n][r] + bias[n]) * uu[n];

    // sum over the 16-lane column group (C/D layout: col = lane&15)
#pragma unroll
    for (int m = 0; m < 4; ++m)
#pragma unroll
        for (int r = 0; r < 4; ++r) {
            float v = psum[m][r];
            v += __shfl_xor(v, 1); v += __shfl_xor(v, 2);
            v += __shfl_xor(v, 4); v += __shfl_xor(v, 8);
            psum[m][r] = v;
        }

    float* partial = reinterpret_cast<float*>(lds);  // 8x64 f32, reuses A buf0 (last step read buf1)
    if (c15 == 0) {
#pragma unroll
        for (int m = 0; m < 4; ++m)
#pragma unroll
            for (int r = 0; r < 4; ++r)
                partial[wid * 64 + m * 16 + hi * 4 + r] = psum[m][r];
    }
    __syncthreads();
    if (tid < 64) {
        float sc = 0.f;
#pragma unroll
        for (int w = 0; w < 8; ++w) sc += partial[w * 64 + tid];
        scores[rowbase + tid] = sc;
    }
}

// ---------------------------------------------------------------------------
// kernel 2: per-batch softmax over n=2048 scores
__global__ void softmax_kernel(const float* __restrict__ scores, float* __restrict__ VU) {
    __shared__ float red[8];
    const int b = blockIdx.x, tid = threadIdx.x;
    const int lane = tid & 63, wid = tid >> 6;
    const float* s = scores + b * N_SEQ;
    float v[8];
    float mx = -3.0e38f;
#pragma unroll
    for (int j = 0; j < 8; ++j) { v[j] = s[tid + j * 256]; mx = fmaxf(mx, v[j]); }
#pragma unroll
    for (int off = 1; off < 64; off <<= 1) mx = fmaxf(mx, __shfl_xor(mx, off));
    if (lane == 0) red[wid] = mx;
    __syncthreads();
    mx = fmaxf(fmaxf(red[0], red[1]), fmaxf(red[2], red[3]));
    float e[8], sum = 0.f;
#pragma unroll
    for (int j = 0; j < 8; ++j) { e[j] = __expf(v[j] - mx); sum += e[j]; }
#pragma unroll
    for (int off = 1; off < 64; off <<= 1) sum += __shfl_xor(sum, off);
    if (lane == 0) red[4 + wid] = sum;
    __syncthreads();
    float total = (red[4] + red[5]) + (red[6] + red[7]);
    float rinv = 1.f / total;
#pragma unroll
    for (int j = 0; j < 8; ++j) VU[b * N_SEQ + tid + j * 256] = e[j] * rinv;
}

// ---------------------------------------------------------------------------
// kernel 3: Ma = H * VU (broadcast over u), float4 vectorized
__global__ void ma_kernel(const float* __restrict__ H, const float* __restrict__ VU,
                          float* __restrict__ Ma) {
    const int stride = gridDim.x * blockDim.x;
    const int n4 = (int)(MA_ELEMS / 4);
    for (int i4 = blockIdx.x * blockDim.x + threadIdx.x; i4 < n4; i4 += stride) {
        float sc = VU[i4 >> 8];                         // 256 float4 per row
        f32x4 h = reinterpret_cast<const f32x4*>(H)[i4];
        reinterpret_cast<f32x4*>(Ma)[i4] = h * sc;
    }
}

// ---------------------------------------------------------------------------
extern "C" void kernel_launch(void* const* d_in, const int* in_sizes, int n_in,
                              void* d_out, int out_size, void* d_ws, size_t ws_size,
                              hipStream_t stream) {
    const float* H  = (const float*)d_in[0];
    const float* W  = (const float*)d_in[1];
    const float* Bb = (const float*)d_in[2];
    const float* Uv = (const float*)d_in[3];

    float* out    = (float*)d_out;
    float* Ma     = out;                       // 67108864 floats
    float* VU     = out + MA_ELEMS;            // 65536 floats
    // scratch inside the Ma region (fully overwritten by ma_kernel last):
    float*  scores = out;                      // 65536 floats  [0, 256KB)
    __bf16* Wp     = (__bf16*)(out + NROWS);   // 524288 bf16   [256KB, 1.25MB)

    wpack_kernel<<<256, 256, 0, stream>>>(W, Wp);
    score_gemm_kernel<<<1024, 512, 0, stream>>>(H, Wp, Bb, Uv, scores);
    softmax_kernel<<<N_BATCH, 256, 0, stream>>>(scores, VU);
    ma_kernel<<<2048, 256, 0, stream>>>(H, VU, Ma);
}

// Round 2
// 222.203 us; speedup vs baseline: 1.0096x; 1.0096x over previous
//
#include <hip/hip_runtime.h>
#include <hip/hip_bf16.h>

typedef __attribute__((ext_vector_type(8))) __bf16 bf16x8;
typedef __attribute__((ext_vector_type(4))) __bf16 bf16x4;
typedef __attribute__((ext_vector_type(4))) float f32x4;

#define N_SEQ   2048
#define N_BATCH 32
#define DIM_U   1024
#define DIM_A   512
#define NROWS   65536
#define MA_ELEMS ((size_t)NROWS * DIM_U) /* 67108864 */

__device__ __forceinline__ float tanh_fast(float x) {
    x = fminf(fmaxf(x, -15.f), 15.f);
    float e = __expf(2.f * x);
    return (e - 1.f) * __builtin_amdgcn_rcpf(e + 1.f);
}

// ---------------------------------------------------------------------------
// kernel 0: pack W (1024x512 f32) into bf16 staging order for the GEMM.
// Flat group g = (((it*2+nh)*2+kk)*4+k16)*256 + col   (it 0..15, nh 0..1,
// kk 0..1, k16 0..3, col 0..255); element j (0..7) is K index
// k = it*64 + kk*32 + k16*8 + j, source column = nh*256 + col.
// Each (it,nh) block is a contiguous 32KB chunk == one GEMM B-stage.
__global__ void wpack_kernel(const float* __restrict__ W, __bf16* __restrict__ Wp) {
    int g = blockIdx.x * 256 + threadIdx.x;          // 0..65535
    int it  = g >> 12;
    int rem = g & 4095;
    int nh  = rem >> 11;
    int kk  = (rem >> 10) & 1;
    int k16 = (rem >> 8) & 3;
    int col = rem & 255;
    int k0 = it * 64 + kk * 32 + k16 * 8;
    int c  = nh * 256 + col;
    bf16x8 o;
#pragma unroll
    for (int j = 0; j < 8; ++j) o[j] = (__bf16)W[(k0 + j) * 512 + c];
    *reinterpret_cast<bf16x8*>(Wp + (size_t)g * 8) = o;
}

// ---------------------------------------------------------------------------
// kernel 1: partial scores. One WG = 128 rows x 256 cols, K=1024 in 16 steps
// of BK=64. 8 waves in 2(M)x4(N) grid; wave owns 64x64 (Mr=4 x Nr=4 frags,
// acc = 64 VGPR). LDS 64KB: A dbuf 2x16KB [kk][k16][row128][16B],
// B 32KB [kk][k16][col256][16B] (restaged per iter; 2 blocks/CU anti-phase
// hides the stage latency, m97 recipe). launch_bounds(512,4) pins VGPR<=128
// so 2 blocks/CU fit.
#define LDSB 32768

__global__ __launch_bounds__(512, 4) void score_gemm_kernel(
    const float* __restrict__ H, const __bf16* __restrict__ Wp,
    const float* __restrict__ Bb, const float* __restrict__ Uv,
    float* __restrict__ sp)
{
    __shared__ __align__(16) char lds[65536];
    const int tid  = threadIdx.x;
    const int lane = tid & 63;
    const int wid  = tid >> 6;     // 0..7
    const int c15  = lane & 15;
    const int hi   = lane >> 4;    // 0..3
    const int wr   = wid >> 2;     // 0..1  (M)
    const int wc   = wid & 3;      // 0..3  (N)

    // XCD-bijective swizzle (1024 WGs % 8 == 0): consecutive logical tiles on
    // one XCD -> Wp (1MB) L2-resident, (mt,0)/(mt,1) pair shares A via L2.
    const int bid = blockIdx.x;
    const int swz = (bid & 7) * 128 + (bid >> 3);
    const int mt = swz >> 1, nh = swz & 1;
    const long rowbase = (long)mt * 128;
    const int  colbase = nh * 256;

    // --- A staging: 512 threads x 2 slots; slot s: row=s>>3, k16g=s&7
    const int s0 = tid, s1 = tid + 512;
    const float* ag0 = H + (rowbase + (s0 >> 3)) * DIM_U + (s0 & 7) * 8;
    const float* ag1 = H + (rowbase + (s1 >> 3)) * DIM_U + (s1 & 7) * 8;
    const int aw0 = ((s0 & 7) >> 2) * 8192 + (s0 & 3) * 2048 + (s0 >> 3) * 16;
    const int aw1 = ((s1 & 7) >> 2) * 8192 + (s1 & 3) * 2048 + (s1 >> 3) * 16;

    // --- B staging: 4 x global_load_lds(16B) per thread per iter
    const __bf16* wpl = Wp + (size_t)nh * 16384 + wid * 512 + lane * 8;

    // frag read offsets
    const int aoff = hi * 2048 + (wr * 64 + c15) * 16;          // + cur*16384 + kk*8192 + m*256
    const int boff = LDSB + hi * 4096 + (wc * 64 + c15) * 16;   // + kk*16384 + n*256

    f32x4 acc[4][4];
#pragma unroll
    for (int m = 0; m < 4; ++m)
#pragma unroll
        for (int n = 0; n < 4; ++n) acc[m][n] = f32x4{0.f, 0.f, 0.f, 0.f};

#define STAGE_A(it_, buf_) {                                                   \
        f32x4 u0 = *reinterpret_cast<const f32x4*>(ag0 + (it_) * 64);          \
        f32x4 u1 = *reinterpret_cast<const f32x4*>(ag0 + (it_) * 64 + 4);      \
        f32x4 v0 = *reinterpret_cast<const f32x4*>(ag1 + (it_) * 64);          \
        f32x4 v1 = *reinterpret_cast<const f32x4*>(ag1 + (it_) * 64 + 4);      \
        bf16x8 p0 = {(__bf16)u0.x,(__bf16)u0.y,(__bf16)u0.z,(__bf16)u0.w,      \
                     (__bf16)u1.x,(__bf16)u1.y,(__bf16)u1.z,(__bf16)u1.w};     \
        bf16x8 p1 = {(__bf16)v0.x,(__bf16)v0.y,(__bf16)v0.z,(__bf16)v0.w,      \
                     (__bf16)v1.x,(__bf16)v1.y,(__bf16)v1.z,(__bf16)v1.w};     \
        *reinterpret_cast<bf16x8*>(lds + (buf_) * 16384 + aw0) = p0;           \
        *reinterpret_cast<bf16x8*>(lds + (buf_) * 16384 + aw1) = p1; }

#define STAGE_B(it_) {                                                         \
        _Pragma("unroll")                                                      \
        for (int i_ = 0; i_ < 4; ++i_)                                         \
            __builtin_amdgcn_global_load_lds(                                  \
                (const __attribute__((address_space(1))) void*)(const void*)   \
                    (wpl + (size_t)(it_) * 32768 + i_ * 4096),                 \
                (__attribute__((address_space(3))) void*)(void*)               \
                    (lds + LDSB + i_ * 8192 + wid * 1024),                     \
                16, 0, 0); }

    // prologue
    STAGE_A(0, 0);
    STAGE_B(0);
    __syncthreads();

    for (int it = 0; it < 16; ++it) {
        const int cur = it & 1;
#pragma unroll
        for (int kk = 0; kk < 2; ++kk) {
            bf16x8 afr[4], bfr[4];
            const char* ab = lds + cur * 16384 + kk * 8192 + aoff;
            const char* bb = lds + kk * 16384 + boff;
#pragma unroll
            for (int m = 0; m < 4; ++m)
                afr[m] = *reinterpret_cast<const bf16x8*>(ab + m * 256);
#pragma unroll
            for (int n = 0; n < 4; ++n)
                bfr[n] = *reinterpret_cast<const bf16x8*>(bb + n * 256);
#pragma unroll
            for (int m = 0; m < 4; ++m)
#pragma unroll
                for (int n = 0; n < 4; ++n)
                    acc[m][n] = __builtin_amdgcn_mfma_f32_16x16x32_bf16(
                        afr[m], bfr[n], acc[m][n], 0, 0, 0);
        }
        __syncthreads();              // everyone done reading B + A[cur^1] slot
        if (it < 15) {
            STAGE_A(it + 1, cur ^ 1);
            STAGE_B(it + 1);
        }
        __syncthreads();              // stage complete (compiler drains cnts)
    }

    // ---- epilogue: tanh(acc + bias) * U, reduce over this WG's 256 cols
    float bias[4], uu[4];
#pragma unroll
    for (int n = 0; n < 4; ++n) {
        int col = colbase + wc * 64 + n * 16 + c15;
        bias[n] = Bb[col];
        uu[n]   = Uv[col];
    }
    float psum[4][4];
#pragma unroll
    for (int m = 0; m < 4; ++m)
#pragma unroll
        for (int r = 0; r < 4; ++r) psum[m][r] = 0.f;
#pragma unroll
    for (int m = 0; m < 4; ++m)
#pragma unroll
        for (int n = 0; n < 4; ++n)
#pragma unroll
            for (int r = 0; r < 4; ++r)
                psum[m][r] += tanh_fast(acc[m][n][r] + bias[n]) * uu[n];

    // reduce across the 16-lane column group (C/D: col = lane&15)
#pragma unroll
    for (int m = 0; m < 4; ++m)
#pragma unroll
        for (int r = 0; r < 4; ++r) {
            float v = psum[m][r];
            v += __shfl_xor(v, 1); v += __shfl_xor(v, 2);
            v += __shfl_xor(v, 4); v += __shfl_xor(v, 8);
            psum[m][r] = v;
        }

    float* partial = reinterpret_cast<float*>(lds);  // 8 x 64 f32
    if (c15 == 0) {
#pragma unroll
        for (int m = 0; m < 4; ++m)
#pragma unroll
            for (int r = 0; r < 4; ++r)
                partial[wid * 64 + m * 16 + hi * 4 + r] = psum[m][r];
    }
    __syncthreads();
    if (tid < 128) {
        // row = tid (0..127); waves wr=tid>>6, wc=0..3 hold its partials
        const int wrr = tid >> 6, rl = tid & 63;
        float sc = 0.f;
#pragma unroll
        for (int w = 0; w < 4; ++w) sc += partial[(wrr * 4 + w) * 64 + rl];
        sp[(size_t)nh * NROWS + rowbase + tid] = sc;
    }
}

// ---------------------------------------------------------------------------
// kernel 2: per-batch softmax over n=2048 (scores = sum of the 2 N-partials)
__global__ void softmax_kernel(const float* __restrict__ sp, float* __restrict__ VU) {
    __shared__ float red[8];
    const int b = blockIdx.x, tid = threadIdx.x;
    const int lane = tid & 63, wid = tid >> 6;
    const float* s0 = sp + b * N_SEQ;
    const float* s1 = sp + NROWS + b * N_SEQ;
    float v[8];
    float mx = -3.0e38f;
#pragma unroll
    for (int j = 0; j < 8; ++j) {
        int x = tid + j * 256;
        v[j] = s0[x] + s1[x];
        mx = fmaxf(mx, v[j]);
    }
#pragma unroll
    for (int off = 1; off < 64; off <<= 1) mx = fmaxf(mx, __shfl_xor(mx, off));
    if (lane == 0) red[wid] = mx;
    __syncthreads();
    mx = fmaxf(fmaxf(red[0], red[1]), fmaxf(red[2], red[3]));
    float e[8], sum = 0.f;
#pragma unroll
    for (int j = 0; j < 8; ++j) { e[j] = __expf(v[j] - mx); sum += e[j]; }
#pragma unroll
    for (int off = 1; off < 64; off <<= 1) sum += __shfl_xor(sum, off);
    if (lane == 0) red[4 + wid] = sum;
    __syncthreads();
    float total = (red[4] + red[5]) + (red[6] + red[7]);
    float rinv = 1.f / total;
#pragma unroll
    for (int j = 0; j < 8; ++j) VU[b * N_SEQ + tid + j * 256] = e[j] * rinv;
}

// ---------------------------------------------------------------------------
// kernel 3: Ma = H * VU (broadcast over u), float4 vectorized
__global__ void ma_kernel(const float* __restrict__ H, const float* __restrict__ VU,
                          float* __restrict__ Ma) {
    const int stride = gridDim.x * blockDim.x;
    const int n4 = (int)(MA_ELEMS / 4);
    for (int i4 = blockIdx.x * blockDim.x + threadIdx.x; i4 < n4; i4 += stride) {
        float sc = VU[i4 >> 8];                         // 256 float4 per row
        f32x4 h = reinterpret_cast<const f32x4*>(H)[i4];
        reinterpret_cast<f32x4*>(Ma)[i4] = h * sc;
    }
}

// ---------------------------------------------------------------------------
extern "C" void kernel_launch(void* const* d_in, const int* in_sizes, int n_in,
                              void* d_out, int out_size, void* d_ws, size_t ws_size,
                              hipStream_t stream) {
    const float* H  = (const float*)d_in[0];
    const float* W  = (const float*)d_in[1];
    const float* Bb = (const float*)d_in[2];
    const float* Uv = (const float*)d_in[3];

    float* out = (float*)d_out;
    float* Ma  = out;                          // 67108864 floats
    float* VU  = out + MA_ELEMS;               // 65536 floats
    // scratch inside the Ma region (ma_kernel overwrites it all at the end):
    float*  sp = out;                          // 2 x 65536 partial scores
    __bf16* Wp = (__bf16*)(out + 2 * NROWS);   // 524288 bf16 (1MB)

    wpack_kernel<<<256, 256, 0, stream>>>(W, Wp);
    score_gemm_kernel<<<1024, 512, 0, stream>>>(H, Wp, Bb, Uv, sp);
    softmax_kernel<<<N_BATCH, 256, 0, stream>>>(sp, VU);
    ma_kernel<<<2048, 256, 0, stream>>>(H, VU, Ma);
}